// Round 3
// baseline (165.622 us; speedup 1.0000x reference)
//
#include <hip/hip_runtime.h>
#include <hip/hip_cooperative_groups.h>
#include <math.h>

namespace cg = cooperative_groups;

#define EPS   1e-6f
#define BB    256
#define NNEG  1000
#define HH    3
#define DD    128
#define NCN   250   // neg_im2cluster values are in [0, min(NUM_CLUSTER)) = [0,250)

// Single cooperative kernel, 256 blocks (one per sample, 1 block/CU):
//  phase 0: 750 centroid rows normalized+transposed into centT [h][d][c]
//           (4 waves/block x 256 blocks = 1024 waves cover 750 rows)
//           + block 0 zeroes the scalar output
//  -- grid.sync() --
//  phase A: se row normalize + positive path (waves 0..2)
//  phase 3: sim[h][c] table, thread c owns cluster c across all 3 hierarchies
//           (3 independent FMA/load chains -> ~24 outstanding L2 loads)
//  phase 4: negative-path loss from LDS (negc prefetched at kernel entry)
//  phase 5: block reduce + one atomicAdd
__global__ __launch_bounds__(256, 1) void k_fused(
        const float* __restrict__ se,
        const float* __restrict__ c0,
        const float* __restrict__ c1,
        const float* __restrict__ c2,
        const int* __restrict__ i2c0,
        const int* __restrict__ i2c1,
        const int* __restrict__ i2c2,
        const int* __restrict__ index,
        const int* __restrict__ negc,
        float* __restrict__ centT,
        float* __restrict__ out) {
    int b = blockIdx.x;
    int tid = threadIdx.x, wave = tid >> 6, lane = tid & 63;

    __shared__ float sse[HH * DD];      // normalized se rows
    __shared__ float ssim[HH * NCN];    // path-factor table
    __shared__ int   snegc[NNEG * HH];  // this sample's negative labels (12 KB)
    __shared__ int   slab[HH];
    __shared__ float ph[HH];
    __shared__ float wL[4], wT[4];

    // --- prefetch negc[b] into LDS (HBM latency overlaps phase 0 + grid sync) ---
    {
        const int4* src = (const int4*)(negc + (size_t)b * (NNEG * HH));
        int4* dst = (int4*)snegc;
        #pragma unroll
        for (int i = tid; i < (NNEG * HH) / 4; i += 256) dst[i] = src[i];
    }

    // --- phase 0: normalize centroid rows 0..249 of each hierarchy -> centT ---
    {
        int wid = b * 4 + wave;                 // 0..1023, rows 0..749 active
        if (wid < HH * NCN) {
            int h = (wid >= 2 * NCN) ? 2 : (wid >= NCN ? 1 : 0);
            int c = wid - h * NCN;
            const float* cp = (h == 0) ? c0 : (h == 1) ? c1 : c2;
            const float2 v = *(const float2*)(cp + (size_t)c * DD + lane * 2);
            float ssq = v.x * v.x + v.y * v.y;
            #pragma unroll
            for (int off = 32; off; off >>= 1) ssq += __shfl_xor(ssq, off);
            float inv = 1.0f / fmaxf(sqrtf(ssq), 1e-12f);
            float* base = centT + h * (DD * NCN);
            base[(lane * 2)     * NCN + c] = v.x * inv;
            base[(lane * 2 + 1) * NCN + c] = v.y * inv;
        }
        if (b == 0 && tid == 0) out[0] = 0.0f;
    }

    // --- phase A: se normalize + positive path (waves 0..2) ---
    if (wave < HH) {
        int h = wave;
        const float2 s = *(const float2*)(se + (size_t)b * (HH * DD) + h * DD + lane * 2);
        float ssq = s.x * s.x + s.y * s.y;
        #pragma unroll
        for (int off = 32; off; off >>= 1) ssq += __shfl_xor(ssq, off);
        float inv = 1.0f / fmaxf(sqrtf(ssq), 1e-12f);
        float2 sn = make_float2(s.x * inv, s.y * inv);
        sse[h * DD + lane * 2]     = sn.x;
        sse[h * DD + lane * 2 + 1] = sn.y;

        int idx = index[b];
        const int*   ip = (h == 0) ? i2c0 : (h == 1) ? i2c1 : i2c2;
        const float* cp = (h == 0) ? c0   : (h == 1) ? c1   : c2;
        int cidx = ip[idx];
        const float2 cv = *(const float2*)(cp + (size_t)cidx * DD + lane * 2);
        float dot = sn.x * cv.x + sn.y * cv.y;
        float csq = cv.x * cv.x + cv.y * cv.y;
        #pragma unroll
        for (int off = 32; off; off >>= 1) {
            dot += __shfl_xor(dot, off);
            csq += __shfl_xor(csq, off);
        }
        if (lane == 0) {
            float invc = 1.0f / fmaxf(sqrtf(csq), 1e-12f);
            ph[h]   = (dot * invc + 1.0f) * 0.5f;
            slab[h] = cidx;
        }
    }

    // make centT visible device-wide, then grid barrier (also block-syncs LDS)
    __threadfence();
    cg::this_grid().sync();

    // --- phase 3: sim table; thread c handles cluster c in all 3 hierarchies ---
    if (tid < NCN) {
        const float* ct0 = centT + 0 * (DD * NCN) + tid;
        const float* ct1 = centT + 1 * (DD * NCN) + tid;
        const float* ct2 = centT + 2 * (DD * NCN) + tid;
        float a0 = 0.0f, a1 = 0.0f, a2 = 0.0f;
        #pragma unroll 8
        for (int d = 0; d < DD; ++d) {
            a0 = fmaf(sse[d],          ct0[(size_t)d * NCN], a0);
            a1 = fmaf(sse[DD + d],     ct1[(size_t)d * NCN], a1);
            a2 = fmaf(sse[2 * DD + d], ct2[(size_t)d * NCN], a2);
        }
        ssim[tid]           = (a0 + 1.0f) * 0.5f;
        ssim[NCN + tid]     = (a1 + 1.0f) * 0.5f;
        ssim[2 * NCN + tid] = (a2 + 1.0f) * 0.5f;
    }
    __syncthreads();

    // --- phase 4: negative-path loss from LDS ---
    int l0 = slab[0], l1 = slab[1], l2 = slab[2];
    float accL = 0.0f, accT = 0.0f;
    for (int n = tid; n < NNEG; n += 256) {
        int i0 = snegc[n * 3], i1 = snegc[n * 3 + 1], i2 = snegc[n * 3 + 2];
        float p = ssim[i0] * ssim[NCN + i1] * ssim[2 * NCN + i2];
        if (i0 != l0 || i1 != l1 || i2 != l2) {
            accL -= logf(1.0f - p + EPS);
            accT += 1.0f;
        }
    }
    #pragma unroll
    for (int off = 32; off; off >>= 1) {
        accL += __shfl_xor(accL, off);
        accT += __shfl_xor(accT, off);
    }
    if (lane == 0) { wL[wave] = accL; wT[wave] = accT; }
    __syncthreads();

    // --- phase 5: combine + atomic ---
    if (tid == 0) {
        float L = wL[0] + wL[1] + wL[2] + wL[3];
        float T = wT[0] + wT[1] + wT[2] + wT[3];
        float neg_b = L / (T + EPS);
        float pos_b = -logf(ph[0] * ph[1] * ph[2] + EPS);
        atomicAdd(out, (pos_b + neg_b) * (1.0f / (2.0f * BB)));
    }
}

extern "C" void kernel_launch(void* const* d_in, const int* in_sizes, int n_in,
                              void* d_out, int out_size, void* d_ws, size_t ws_size,
                              hipStream_t stream) {
    const float* se    = (const float*)d_in[0];
    const float* c0    = (const float*)d_in[1];
    const float* c1    = (const float*)d_in[2];
    const float* c2    = (const float*)d_in[3];
    const int*   i2c0  = (const int*)d_in[4];
    const int*   i2c1  = (const int*)d_in[5];
    const int*   i2c2  = (const int*)d_in[6];
    const int*   index = (const int*)d_in[7];
    const int*   negc  = (const int*)d_in[8];

    float* centT = (float*)d_ws;    // 96000 floats, [h][d][c]
    float* out   = (float*)d_out;

    void* args[] = {
        (void*)&se, (void*)&c0, (void*)&c1, (void*)&c2,
        (void*)&i2c0, (void*)&i2c1, (void*)&i2c2,
        (void*)&index, (void*)&negc, (void*)&centT, (void*)&out
    };
    hipLaunchCooperativeKernel((const void*)k_fused, dim3(BB), dim3(256),
                               args, 0, stream);
}

// Round 4
// 95.340 us; speedup vs baseline: 1.7372x; 1.7372x over previous
//
#include <hip/hip_runtime.h>
#include <math.h>

#define EPS   1e-6f
#define BB    256
#define NNEG  1000
#define HH    3
#define DD    128
#define NCN   250   // neg_im2cluster values are in [0, min(NUM_CLUSTER)) = [0,250)

// kA: normalize centroid rows 0..249 of each hierarchy into transposed
// [h][d][c] layout in d_ws; zero the scalar output. Kernel boundary (not a
// grid sync) hands centT to kB — cross-XCD visibility for free.
__global__ void kA_prep(const float* __restrict__ c0,
                        const float* __restrict__ c1,
                        const float* __restrict__ c2,
                        float* __restrict__ centT,
                        float* __restrict__ out) {
    if (blockIdx.x == 0 && threadIdx.x == 0) out[0] = 0.0f;
    int wid  = blockIdx.x * 4 + (threadIdx.x >> 6);
    int lane = threadIdx.x & 63;
    if (wid >= HH * NCN) return;
    int h = (wid >= 2 * NCN) ? 2 : (wid >= NCN ? 1 : 0);
    int c = wid - h * NCN;
    const float* cp = (h == 0) ? c0 : (h == 1) ? c1 : c2;
    const float2 v = *(const float2*)(cp + (size_t)c * DD + lane * 2);
    float ss = v.x * v.x + v.y * v.y;
    #pragma unroll
    for (int off = 32; off; off >>= 1) ss += __shfl_xor(ss, off);
    float inv = 1.0f / fmaxf(sqrtf(ss), 1e-12f);
    float* base = centT + h * (DD * NCN);
    base[(lane * 2)     * NCN + c] = v.x * inv;
    base[(lane * 2 + 1) * NCN + c] = v.y * inv;
}

// kB: one block (512 threads = 8 waves) per sample b.
//  entry : prefetch negc[b] -> LDS (overlaps phase A)
//  phase A: se normalize + positive path (waves 0..2)
//  phase 3: sim[h][c] table from L2-hot centT (coalesced stride-NCN reads)
//  phase 4: negative-path loss via LDS lookups
//  phase 5: block reduce + one atomicAdd
__global__ __launch_bounds__(512) void kB_main(
        const float* __restrict__ se,
        const float* __restrict__ c0,
        const float* __restrict__ c1,
        const float* __restrict__ c2,
        const int* __restrict__ i2c0,
        const int* __restrict__ i2c1,
        const int* __restrict__ i2c2,
        const int* __restrict__ index,
        const int* __restrict__ negc,
        const float* __restrict__ centT,
        float* __restrict__ out) {
    int b = blockIdx.x;
    int tid = threadIdx.x, wave = tid >> 6, lane = tid & 63;

    __shared__ float sse[HH * DD];
    __shared__ float ssim[HH * NCN];
    __shared__ int   snegc[NNEG * HH];   // 12 KB
    __shared__ int   slab[HH];
    __shared__ float ph[HH];
    __shared__ float wL[8], wT[8];

    // --- prefetch this sample's negative labels into LDS ---
    {
        const int4* src = (const int4*)(negc + (size_t)b * (NNEG * HH));
        int4* dst = (int4*)snegc;
        #pragma unroll
        for (int i = tid; i < (NNEG * HH) / 4; i += 512) dst[i] = src[i];
    }

    // --- phase A: se normalize + positive path (waves 0..2) ---
    if (wave < HH) {
        int h = wave;
        const float2 s = *(const float2*)(se + (size_t)b * (HH * DD) + h * DD + lane * 2);
        float ssq = s.x * s.x + s.y * s.y;
        #pragma unroll
        for (int off = 32; off; off >>= 1) ssq += __shfl_xor(ssq, off);
        float inv = 1.0f / fmaxf(sqrtf(ssq), 1e-12f);
        float2 sn = make_float2(s.x * inv, s.y * inv);
        sse[h * DD + lane * 2]     = sn.x;
        sse[h * DD + lane * 2 + 1] = sn.y;

        int idx = index[b];
        const int*   ip = (h == 0) ? i2c0 : (h == 1) ? i2c1 : i2c2;
        const float* cp = (h == 0) ? c0   : (h == 1) ? c1   : c2;
        int cidx = ip[idx];
        const float2 cv = *(const float2*)(cp + (size_t)cidx * DD + lane * 2);
        float dot = sn.x * cv.x + sn.y * cv.y;
        float csq = cv.x * cv.x + cv.y * cv.y;
        #pragma unroll
        for (int off = 32; off; off >>= 1) {
            dot += __shfl_xor(dot, off);
            csq += __shfl_xor(csq, off);
        }
        if (lane == 0) {
            float invc = 1.0f / fmaxf(sqrtf(csq), 1e-12f);
            ph[h]   = (dot * invc + 1.0f) * 0.5f;
            slab[h] = cidx;
        }
    }
    __syncthreads();

    // --- phase 3: sim table, 750 dots spread over 512 threads ---
    for (int j = tid; j < HH * NCN; j += 512) {
        int h = (j >= 2 * NCN) ? 2 : (j >= NCN ? 1 : 0);
        int c = j - h * NCN;
        const float* ct = centT + h * (DD * NCN) + c;
        const float* sh = sse + h * DD;
        float acc = 0.0f;
        #pragma unroll 8
        for (int d = 0; d < DD; ++d) acc = fmaf(sh[d], ct[(size_t)d * NCN], acc);
        ssim[j] = (acc + 1.0f) * 0.5f;
    }
    __syncthreads();

    // --- phase 4: negative-path loss ---
    int l0 = slab[0], l1 = slab[1], l2 = slab[2];
    float accL = 0.0f, accT = 0.0f;
    for (int n = tid; n < NNEG; n += 512) {
        int i0 = snegc[n * 3], i1 = snegc[n * 3 + 1], i2 = snegc[n * 3 + 2];
        float p = ssim[i0] * ssim[NCN + i1] * ssim[2 * NCN + i2];
        if (i0 != l0 || i1 != l1 || i2 != l2) {
            accL -= logf(1.0f - p + EPS);
            accT += 1.0f;
        }
    }
    #pragma unroll
    for (int off = 32; off; off >>= 1) {
        accL += __shfl_xor(accL, off);
        accT += __shfl_xor(accT, off);
    }
    if (lane == 0) { wL[wave] = accL; wT[wave] = accT; }
    __syncthreads();

    // --- phase 5: combine + atomic ---
    if (tid == 0) {
        float L = 0.0f, T = 0.0f;
        #pragma unroll
        for (int w = 0; w < 8; ++w) { L += wL[w]; T += wT[w]; }
        float neg_b = L / (T + EPS);
        float pos_b = -logf(ph[0] * ph[1] * ph[2] + EPS);
        atomicAdd(out, (pos_b + neg_b) * (1.0f / (2.0f * BB)));
    }
}

extern "C" void kernel_launch(void* const* d_in, const int* in_sizes, int n_in,
                              void* d_out, int out_size, void* d_ws, size_t ws_size,
                              hipStream_t stream) {
    const float* se    = (const float*)d_in[0];
    const float* c0    = (const float*)d_in[1];
    const float* c1    = (const float*)d_in[2];
    const float* c2    = (const float*)d_in[3];
    const int*   i2c0  = (const int*)d_in[4];
    const int*   i2c1  = (const int*)d_in[5];
    const int*   i2c2  = (const int*)d_in[6];
    const int*   index = (const int*)d_in[7];
    const int*   negc  = (const int*)d_in[8];

    float* centT = (float*)d_ws;    // 96000 floats, [h][d][c]
    float* out   = (float*)d_out;

    hipLaunchKernelGGL(kA_prep, dim3((HH * NCN + 3) / 4), dim3(256), 0, stream,
                       c0, c1, c2, centT, out);
    hipLaunchKernelGGL(kB_main, dim3(BB), dim3(512), 0, stream,
                       se, c0, c1, c2, i2c0, i2c1, i2c2, index, negc, centT, out);
}

// Round 5
// 91.216 us; speedup vs baseline: 1.8157x; 1.0452x over previous
//
#include <hip/hip_runtime.h>
#include <math.h>

#define EPS   1e-6f
#define BB    256
#define NNEG  1000
#define HH    3
#define DD    128
#define NCN   250   // neg_im2cluster values are in [0, min(NUM_CLUSTER)) = [0,250)

// kA: normalize centroid rows 0..249 of each hierarchy into transposed
// [h][d][c] layout in d_ws; zero the scalar output. Kernel boundary (not a
// grid sync) hands centT to kB — cross-XCD visibility for free (R3 lesson:
// grid.sync + threadfence cost 65 us; a kernel boundary is ~2 us).
__global__ void kA_prep(const float* __restrict__ c0,
                        const float* __restrict__ c1,
                        const float* __restrict__ c2,
                        float* __restrict__ centT,
                        float* __restrict__ out) {
    if (blockIdx.x == 0 && threadIdx.x == 0) out[0] = 0.0f;
    int wid  = blockIdx.x * 4 + (threadIdx.x >> 6);
    int lane = threadIdx.x & 63;
    if (wid >= HH * NCN) return;
    int h = (wid >= 2 * NCN) ? 2 : (wid >= NCN ? 1 : 0);
    int c = wid - h * NCN;
    const float* cp = (h == 0) ? c0 : (h == 1) ? c1 : c2;
    const float2 v = *(const float2*)(cp + (size_t)c * DD + lane * 2);
    float ss = v.x * v.x + v.y * v.y;
    #pragma unroll
    for (int off = 32; off; off >>= 1) ss += __shfl_xor(ss, off);
    float inv = 1.0f / fmaxf(sqrtf(ss), 1e-12f);
    float* base = centT + h * (DD * NCN);
    base[(lane * 2)     * NCN + c] = v.x * inv;
    base[(lane * 2 + 1) * NCN + c] = v.y * inv;
}

// kB: one block (512 threads = 8 waves) per sample b.
//  entry : prefetch negc[b] -> LDS (HBM latency overlaps phase A)
//  phase A: se normalize + positive path (waves 0..2)
//  phase 3: sim table, 2 adjacent clusters per thread: one ds_read_b128 of
//           se feeds 8 FMAs (halves LDS-pipe pressure vs 1 cluster/thread),
//           float2 loads over adjacent clusters stay lane-coalesced (512 B/instr)
//  phase 4: negative-path loss via LDS lookups
//  phase 5: block reduce + one atomicAdd
__global__ __launch_bounds__(512) void kB_main(
        const float* __restrict__ se,
        const float* __restrict__ c0,
        const float* __restrict__ c1,
        const float* __restrict__ c2,
        const int* __restrict__ i2c0,
        const int* __restrict__ i2c1,
        const int* __restrict__ i2c2,
        const int* __restrict__ index,
        const int* __restrict__ negc,
        const float* __restrict__ centT,
        float* __restrict__ out) {
    int b = blockIdx.x;
    int tid = threadIdx.x, wave = tid >> 6, lane = tid & 63;

    __shared__ float sse[HH * DD];
    __shared__ float ssim[HH * NCN];
    __shared__ int   snegc[NNEG * HH];   // 12 KB
    __shared__ int   slab[HH];
    __shared__ float ph[HH];
    __shared__ float wL[8], wT[8];

    // --- prefetch this sample's negative labels into LDS ---
    {
        const int4* src = (const int4*)(negc + (size_t)b * (NNEG * HH));
        int4* dst = (int4*)snegc;
        #pragma unroll
        for (int i = tid; i < (NNEG * HH) / 4; i += 512) dst[i] = src[i];
    }

    // --- phase A: se normalize + positive path (waves 0..2) ---
    if (wave < HH) {
        int h = wave;
        const float2 s = *(const float2*)(se + (size_t)b * (HH * DD) + h * DD + lane * 2);
        float ssq = s.x * s.x + s.y * s.y;
        #pragma unroll
        for (int off = 32; off; off >>= 1) ssq += __shfl_xor(ssq, off);
        float inv = 1.0f / fmaxf(sqrtf(ssq), 1e-12f);
        float2 sn = make_float2(s.x * inv, s.y * inv);
        sse[h * DD + lane * 2]     = sn.x;
        sse[h * DD + lane * 2 + 1] = sn.y;

        int idx = index[b];
        const int*   ip = (h == 0) ? i2c0 : (h == 1) ? i2c1 : i2c2;
        const float* cp = (h == 0) ? c0   : (h == 1) ? c1   : c2;
        int cidx = ip[idx];
        const float2 cv = *(const float2*)(cp + (size_t)cidx * DD + lane * 2);
        float dot = sn.x * cv.x + sn.y * cv.y;
        float csq = cv.x * cv.x + cv.y * cv.y;
        #pragma unroll
        for (int off = 32; off; off >>= 1) {
            dot += __shfl_xor(dot, off);
            csq += __shfl_xor(csq, off);
        }
        if (lane == 0) {
            float invc = 1.0f / fmaxf(sqrtf(csq), 1e-12f);
            ph[h]   = (dot * invc + 1.0f) * 0.5f;
            slab[h] = cidx;
        }
    }
    __syncthreads();

    // --- phase 3: sim table, thread handles clusters {2p, 2p+1} of hierarchy h ---
    if (tid < HH * (NCN / 2)) {          // 375 tasks, waves 0..5
        int h = tid / (NCN / 2);
        int p = tid - h * (NCN / 2);
        const float2* ct  = (const float2*)(centT + h * (DD * NCN)) + p; // stride NCN/2 float2 per d
        const float4* sh4 = (const float4*)(sse + h * DD);
        float dA = 0.0f, dB = 0.0f;
        #pragma unroll 4
        for (int dq = 0; dq < DD / 4; ++dq) {
            float4 s4 = sh4[dq];
            float2 v0 = ct[0 * (NCN / 2)];
            float2 v1 = ct[1 * (NCN / 2)];
            float2 v2 = ct[2 * (NCN / 2)];
            float2 v3 = ct[3 * (NCN / 2)];
            ct += 4 * (NCN / 2);
            dA = fmaf(s4.x, v0.x, dA); dB = fmaf(s4.x, v0.y, dB);
            dA = fmaf(s4.y, v1.x, dA); dB = fmaf(s4.y, v1.y, dB);
            dA = fmaf(s4.z, v2.x, dA); dB = fmaf(s4.z, v2.y, dB);
            dA = fmaf(s4.w, v3.x, dA); dB = fmaf(s4.w, v3.y, dB);
        }
        ssim[h * NCN + 2 * p]     = (dA + 1.0f) * 0.5f;
        ssim[h * NCN + 2 * p + 1] = (dB + 1.0f) * 0.5f;
    }
    __syncthreads();

    // --- phase 4: negative-path loss ---
    int l0 = slab[0], l1 = slab[1], l2 = slab[2];
    float accL = 0.0f, accT = 0.0f;
    #pragma unroll
    for (int k = 0; k < NNEG / 512 + 1; ++k) {
        int n = tid + k * 512;
        if (n < NNEG) {
            int i0 = snegc[n * 3], i1 = snegc[n * 3 + 1], i2 = snegc[n * 3 + 2];
            float p = ssim[i0] * ssim[NCN + i1] * ssim[2 * NCN + i2];
            if (i0 != l0 || i1 != l1 || i2 != l2) {
                accL -= logf(1.0f - p + EPS);
                accT += 1.0f;
            }
        }
    }
    #pragma unroll
    for (int off = 32; off; off >>= 1) {
        accL += __shfl_xor(accL, off);
        accT += __shfl_xor(accT, off);
    }
    if (lane == 0) { wL[wave] = accL; wT[wave] = accT; }
    __syncthreads();

    // --- phase 5: combine + atomic ---
    if (tid == 0) {
        float L = 0.0f, T = 0.0f;
        #pragma unroll
        for (int w = 0; w < 8; ++w) { L += wL[w]; T += wT[w]; }
        float neg_b = L / (T + EPS);
        float pos_b = -logf(ph[0] * ph[1] * ph[2] + EPS);
        atomicAdd(out, (pos_b + neg_b) * (1.0f / (2.0f * BB)));
    }
}

extern "C" void kernel_launch(void* const* d_in, const int* in_sizes, int n_in,
                              void* d_out, int out_size, void* d_ws, size_t ws_size,
                              hipStream_t stream) {
    const float* se    = (const float*)d_in[0];
    const float* c0    = (const float*)d_in[1];
    const float* c1    = (const float*)d_in[2];
    const float* c2    = (const float*)d_in[3];
    const int*   i2c0  = (const int*)d_in[4];
    const int*   i2c1  = (const int*)d_in[5];
    const int*   i2c2  = (const int*)d_in[6];
    const int*   index = (const int*)d_in[7];
    const int*   negc  = (const int*)d_in[8];

    float* centT = (float*)d_ws;    // 96000 floats, [h][d][c]
    float* out   = (float*)d_out;

    hipLaunchKernelGGL(kA_prep, dim3((HH * NCN + 3) / 4), dim3(256), 0, stream,
                       c0, c1, c2, centT, out);
    hipLaunchKernelGGL(kB_main, dim3(BB), dim3(512), 0, stream,
                       se, c0, c1, c2, i2c0, i2c1, i2c2, index, negc, centT, out);
}